// Round 2
// baseline (1872.858 us; speedup 1.0000x reference)
//
#include <hip/hip_runtime.h>
#include <math.h>

#define T_STEPS 5
#define BATCH 32

// ---------------------------------------------------------------------------
// All-Cout tiled 5x5 VALID conv, fp32, NCHW.
// Block = 256 threads = 32 cols x 8 row-groups (2 rows each) -> 32x16 tile.
// Each block computes ALL COUT channels for its (n, tile): acc[COUT][2].
// Per ci: stage 20x36 input patch once (amortized over COUT), per-thread
// 6x5 window -> registers via conflict-free b32 reads, then COUT*25*2
// fully-unrolled FMAs with weights from block-uniform (scalar) loads.
// ---------------------------------------------------------------------------
template <int CIN, int COUT>
__global__ __launch_bounds__(256) void conv5_allco(
    const float* __restrict__ in, const float* __restrict__ wgt,
    float* __restrict__ out, int Hin, int Win, int Hout, int Wout,
    int tiles_w) {
  __shared__ float lds[20 * 36];
  const int tid = threadIdx.x;
  const int col = tid & 31;   // 0..31 output col within tile
  const int rg = tid >> 5;    // 0..7 row-group (2 output rows)
  const int tw = blockIdx.x % tiles_w;
  const int th = blockIdx.x / tiles_w;
  const int n = blockIdx.y;
  const int ho0 = th * 16, wo0 = tw * 32;

  float acc[COUT][2];
#pragma unroll
  for (int co = 0; co < COUT; ++co) {
    acc[co][0] = 0.f;
    acc[co][1] = 0.f;
  }

  for (int ci = 0; ci < CIN; ++ci) {
    __syncthreads();  // previous iteration's reads done before overwrite
    const float* ip = in + (n * CIN + ci) * Hin * Win;
    for (int i = tid; i < 20 * 36; i += 256) {
      int r = i / 36;
      int c = i - r * 36;
      int gr = ho0 + r, gc = wo0 + c;
      float v = 0.f;
      if (gr < Hin && gc < Win) v = ip[gr * Win + gc];
      lds[r * 36 + c] = v;
    }
    __syncthreads();

    // per-thread input window: rows 2*rg .. 2*rg+5, cols col .. col+4
    float xin[6][5];
#pragma unroll
    for (int rr = 0; rr < 6; ++rr)
#pragma unroll
      for (int cc = 0; cc < 5; ++cc)
        xin[rr][cc] = lds[(rg * 2 + rr) * 36 + col + cc];

#pragma unroll
    for (int kh = 0; kh < 5; ++kh)
#pragma unroll
      for (int kw = 0; kw < 5; ++kw) {
#pragma unroll
        for (int co = 0; co < COUT; ++co) {
          float w = wgt[(co * CIN + ci) * 25 + kh * 5 + kw];  // uniform->s_load
          acc[co][0] = fmaf(xin[kh][kw], w, acc[co][0]);
          acc[co][1] = fmaf(xin[kh + 1][kw], w, acc[co][1]);
        }
      }
  }

  const int wo = wo0 + col;
  const int ho = ho0 + rg * 2;
  if (wo < Wout) {
#pragma unroll
    for (int co = 0; co < COUT; ++co) {
      float* op = out + (n * COUT + co) * Hout * Wout;
      if (ho < Hout) op[ho * Wout + wo] = acc[co][0];
      if (ho + 1 < Hout) op[(ho + 1) * Wout + wo] = acc[co][1];
    }
  }
}

// conv4: (160,32,12,12) -> (160,64,8,8). Block per n: 64 px x 4 co-lanes
// (16 co each, wave-uniform co-group -> scalar weight loads).
__global__ __launch_bounds__(256) void conv4_lds(
    const float* __restrict__ in, const float* __restrict__ wgt,
    float* __restrict__ out) {
  __shared__ float lds[144];
  const int tid = threadIdx.x;
  const int px = tid & 63, cog = tid >> 6;
  const int pr = px >> 3, pc = px & 7;
  const int n = blockIdx.x;
  float acc[16];
#pragma unroll
  for (int j = 0; j < 16; ++j) acc[j] = 0.f;
  for (int ci = 0; ci < 32; ++ci) {
    __syncthreads();
    if (tid < 144) lds[tid] = in[(n * 32 + ci) * 144 + tid];
    __syncthreads();
    float xin[5][5];
#pragma unroll
    for (int rr = 0; rr < 5; ++rr)
#pragma unroll
      for (int cc = 0; cc < 5; ++cc) xin[rr][cc] = lds[(pr + rr) * 12 + pc + cc];
#pragma unroll
    for (int k = 0; k < 25; ++k) {
#pragma unroll
      for (int j = 0; j < 16; ++j) {
        float w = wgt[((cog * 16 + j) * 32 + ci) * 25 + k];
        acc[j] = fmaf(xin[k / 5][k % 5], w, acc[j]);
      }
    }
  }
  float* op = out + (n * 64 + cog * 16) * 64 + px;
#pragma unroll
  for (int j = 0; j < 16; ++j) op[j * 64] = acc[j];
}

// BN stats: two-stage deterministic partial sums in double ------------------
__global__ __launch_bounds__(256) void bn_partial(
    const float* __restrict__ y, int C, int M, int HW, double inv_hw,
    double* __restrict__ psum, double* __restrict__ psq, int S) {
  const int c = blockIdx.x / S;
  const int s = blockIdx.x - c * S;
  const int tid = threadIdx.x;
  double sum = 0.0, sumsq = 0.0;
  for (int i = s * 256 + tid; i < M; i += S * 256) {
    int n = (int)((double)i * inv_hw);
    int hw = i - n * HW;
    if (hw < 0) { n--; hw += HW; }
    else if (hw >= HW) { n++; hw -= HW; }
    float v = y[((long)n * C + c) * (long)HW + hw];
    sum += (double)v;
    sumsq += (double)v * (double)v;
  }
  __shared__ double ls[256], ls2[256];
  ls[tid] = sum;
  ls2[tid] = sumsq;
  __syncthreads();
  for (int off = 128; off > 0; off >>= 1) {
    if (tid < off) {
      ls[tid] += ls[tid + off];
      ls2[tid] += ls2[tid + off];
    }
    __syncthreads();
  }
  if (tid == 0) {
    psum[blockIdx.x] = ls[0];
    psq[blockIdx.x] = ls2[0];
  }
}

__global__ void bn_finalize(const double* __restrict__ psum,
                            const double* __restrict__ psq,
                            const float* __restrict__ gamma,
                            const float* __restrict__ beta,
                            float* __restrict__ scale,
                            float* __restrict__ shift, int C, int S,
                            double invM) {
  int c = threadIdx.x;
  if (c >= C) return;
  double s = 0.0, s2 = 0.0;
  for (int i = 0; i < S; ++i) {
    s += psum[c * S + i];
    s2 += psq[c * S + i];
  }
  double m = s * invM;
  double var = s2 * invM - m * m;
  double r = 1.0 / sqrt(var + 1e-5);
  double sc = (double)gamma[c] * r;
  scale[c] = (float)sc;
  shift[c] = (float)((double)beta[c] - m * sc);
}

// Fused BN-affine + 5-step PLIF + 2x2 maxpool -------------------------------
__global__ __launch_bounds__(256) void plif_pool(
    const float* __restrict__ y, const float* __restrict__ scale,
    const float* __restrict__ shift, const float* __restrict__ wlif,
    float* __restrict__ p, int C, int H, int W, int PH, int PW,
    long t_stride) {
  int idx = blockIdx.x * 256 + threadIdx.x;
  int total = BATCH * C * PH * PW;
  if (idx >= total) return;
  int pw = idx % PW;
  int t2 = idx / PW;
  int ph = t2 % PH;
  t2 /= PH;
  int c = t2 % C;
  int b = t2 / C;
  const float sc = scale[c], sh = shift[c];
  const float decay = 1.f / (1.f + expf(-wlif[0]));
  const long base = (((long)b * C + c) * H + 2 * ph) * W + 2 * pw;
  const long pbase = (((long)b * C + c) * PH + ph) * PW + pw;
  const long pstr = (long)BATCH * C * PH * PW;
  float v0 = 0.f, v1 = 0.f, v2 = 0.f, v3 = 0.f;
#pragma unroll
  for (int t = 0; t < T_STEPS; ++t) {
    const float* yp = y + t * t_stride + base;
    float x0 = yp[0] * sc + sh;
    float x1 = yp[1] * sc + sh;
    float x2 = yp[W] * sc + sh;
    float x3 = yp[W + 1] * sc + sh;
    v0 += (x0 - v0) * decay;
    v1 += (x1 - v1) * decay;
    v2 += (x2 - v2) * decay;
    v3 += (x3 - v3) * decay;
    float s0 = (v0 >= 1.f) ? 1.f : 0.f;
    float s1 = (v1 >= 1.f) ? 1.f : 0.f;
    float s2 = (v2 >= 1.f) ? 1.f : 0.f;
    float s3 = (v3 >= 1.f) ? 1.f : 0.f;
    v0 = (v0 >= 1.f) ? 0.f : v0;
    v1 = (v1 >= 1.f) ? 0.f : v1;
    v2 = (v2 >= 1.f) ? 0.f : v2;
    v3 = (v3 >= 1.f) ? 0.f : v3;
    p[t * pstr + pbase] = fmaxf(fmaxf(s0, s1), fmaxf(s2, s3));
  }
}

// FC: out[n,o] = dot(x[n,:], w[o,:]) (bias added in PLIF). ------------------
__global__ __launch_bounds__(256) void fc_kernel(const float* __restrict__ x,
                                                 const float* __restrict__ w,
                                                 float* __restrict__ out,
                                                 int K, int O, int obpn) {
  int n = blockIdx.x / obpn;
  int o = (blockIdx.x - n * obpn) * 256 + threadIdx.x;
  if (o >= O) return;
  const float4* xr = reinterpret_cast<const float4*>(x + (long)n * K);
  const float4* wr = reinterpret_cast<const float4*>(w + (long)o * K);
  float acc = 0.f;
  for (int k = 0; k < K / 4; ++k) {
    float4 a = xr[k];
    float4 b = wr[k];
    acc += a.x * b.x + a.y * b.y + a.z * b.z + a.w * b.w;
  }
  out[(long)n * O + o] = acc;
}

// PLIF over time for FC activations (adds bias), writes spike seq -----------
__global__ __launch_bounds__(256) void plif_fc(const float* __restrict__ h,
                                               const float* __restrict__ bias,
                                               const float* __restrict__ wlif,
                                               float* __restrict__ s_out,
                                               int F) {
  int idx = blockIdx.x * 256 + threadIdx.x;
  if (idx >= BATCH * F) return;
  int f = idx % F;
  int b = idx / F;
  const float decay = 1.f / (1.f + expf(-wlif[0]));
  const float bi = bias[f];
  float v = 0.f;
#pragma unroll
  for (int t = 0; t < T_STEPS; ++t) {
    long off = ((long)(t * BATCH + b)) * F + f;
    float x = h[off] + bi;
    v += (x - v) * decay;
    float s = (v >= 1.f) ? 1.f : 0.f;
    v = (v >= 1.f) ? 0.f : v;
    s_out[off] = s;
  }
}

// Final PLIF + mean over T --------------------------------------------------
__global__ __launch_bounds__(256) void plif_mean(const float* __restrict__ h,
                                                 const float* __restrict__ bias,
                                                 const float* __restrict__ wlif,
                                                 float* __restrict__ out,
                                                 int O) {
  int idx = blockIdx.x * 256 + threadIdx.x;
  if (idx >= BATCH * O) return;
  int o = idx % O;
  int b = idx / O;
  const float decay = 1.f / (1.f + expf(-wlif[0]));
  const float bi = bias[o];
  float v = 0.f, sum = 0.f;
#pragma unroll
  for (int t = 0; t < T_STEPS; ++t) {
    float x = h[(long)(t * BATCH + b) * O + o] + bi;
    v += (x - v) * decay;
    float s = (v >= 1.f) ? 1.f : 0.f;
    v = (v >= 1.f) ? 0.f : v;
    sum += s;
  }
  out[(long)b * O + o] = sum / 5.0f;
}

// ---------------------------------------------------------------------------
extern "C" void kernel_launch(void* const* d_in, const int* in_sizes, int n_in,
                              void* d_out, int out_size, void* d_ws,
                              size_t ws_size, hipStream_t stream) {
  const float* x = (const float*)d_in[0];
  const float* wc1 = (const float*)d_in[1];
  const float* wc2 = (const float*)d_in[2];
  const float* wc3 = (const float*)d_in[3];
  const float* wc4 = (const float*)d_in[4];
  const float* g1 = (const float*)d_in[5];
  const float* b1 = (const float*)d_in[6];
  const float* g2 = (const float*)d_in[7];
  const float* b2 = (const float*)d_in[8];
  const float* g3 = (const float*)d_in[9];
  const float* b3 = (const float*)d_in[10];
  const float* g4 = (const float*)d_in[11];
  const float* b4 = (const float*)d_in[12];
  const float* wl1 = (const float*)d_in[13];
  const float* wl2 = (const float*)d_in[14];
  const float* wl3 = (const float*)d_in[15];
  const float* wl4 = (const float*)d_in[16];
  const float* wl5 = (const float*)d_in[17];
  const float* wl6 = (const float*)d_in[18];
  const float* fc1w = (const float*)d_in[19];
  const float* fc1b = (const float*)d_in[20];
  const float* fc2w = (const float*)d_in[21];
  const float* fc2b = (const float*)d_in[22];
  float* out = (float*)d_out;

  char* ws = (char*)d_ws;
  float* Y = (float*)ws;
  float* P = (float*)(ws + 68894720);
  char* Sb = ws + 68894720 + 39362560;
  double* psum = (double*)Sb;
  double* psq = psum + 64 * 32;
  float* scale = (float*)(psq + 64 * 32);
  float* shift = scale + 64;

  const int S = 32;

  // ---- block 1: conv1 on B=32 only (input replicated over T) ----
  conv5_allco<3, 16><<<dim3(4 * 8, 32), 256, 0, stream>>>(
      x, wc1, Y, 128, 128, 124, 124, 4);
  {
    int HW = 124 * 124, M = 32 * HW;
    bn_partial<<<16 * S, 256, 0, stream>>>(Y, 16, M, HW, 1.0 / HW, psum, psq, S);
    bn_finalize<<<1, 64, 0, stream>>>(psum, psq, g1, b1, scale, shift, 16, S,
                                      1.0 / (double)M);
  }
  {
    int total = BATCH * 16 * 62 * 62;
    plif_pool<<<(total + 255) / 256, 256, 0, stream>>>(
        Y, scale, shift, wl1, P, 16, 124, 124, 62, 62, 0L);
  }

  // ---- block 2: conv2 (160,16,62,62) -> (160,32,58,58) ----
  conv5_allco<16, 32><<<dim3(2 * 4, 160), 256, 0, stream>>>(
      P, wc2, Y, 62, 62, 58, 58, 2);
  {
    int HW = 58 * 58, M = 160 * HW;
    bn_partial<<<32 * S, 256, 0, stream>>>(Y, 32, M, HW, 1.0 / HW, psum, psq, S);
    bn_finalize<<<1, 64, 0, stream>>>(psum, psq, g2, b2, scale, shift, 32, S,
                                      1.0 / (double)M);
  }
  {
    int total = BATCH * 32 * 29 * 29;
    plif_pool<<<(total + 255) / 256, 256, 0, stream>>>(
        Y, scale, shift, wl2, P, 32, 58, 58, 29, 29, (long)BATCH * 32 * 58 * 58);
  }

  // ---- block 3: conv3 (160,32,29,29) -> (160,32,25,25) ----
  conv5_allco<32, 32><<<dim3(1 * 2, 160), 256, 0, stream>>>(
      P, wc3, Y, 29, 29, 25, 25, 1);
  {
    int HW = 25 * 25, M = 160 * HW;
    bn_partial<<<32 * S, 256, 0, stream>>>(Y, 32, M, HW, 1.0 / HW, psum, psq, S);
    bn_finalize<<<1, 64, 0, stream>>>(psum, psq, g3, b3, scale, shift, 32, S,
                                      1.0 / (double)M);
  }
  {
    int total = BATCH * 32 * 12 * 12;
    plif_pool<<<(total + 255) / 256, 256, 0, stream>>>(
        Y, scale, shift, wl3, P, 32, 25, 25, 12, 12, (long)BATCH * 32 * 25 * 25);
  }

  // ---- block 4: conv4 (160,32,12,12) -> (160,64,8,8) ----
  conv4_lds<<<160, 256, 0, stream>>>(P, wc4, Y);
  {
    int HW = 8 * 8, M = 160 * HW;
    bn_partial<<<64 * S, 256, 0, stream>>>(Y, 64, M, HW, 1.0 / HW, psum, psq, S);
    bn_finalize<<<1, 64, 0, stream>>>(psum, psq, g4, b4, scale, shift, 64, S,
                                      1.0 / (double)M);
  }
  {
    int total = BATCH * 64 * 4 * 4;
    plif_pool<<<(total + 255) / 256, 256, 0, stream>>>(
        Y, scale, shift, wl4, P, 64, 8, 8, 4, 4, (long)BATCH * 64 * 8 * 8);
  }

  // ---- FC head ----
  float* h1 = Y;
  float* s1 = P;
  float* h2 = Y + 163840;
  fc_kernel<<<160 * 4, 256, 0, stream>>>(P, fc1w, h1, 1024, 1024, 4);
  plif_fc<<<(BATCH * 1024 + 255) / 256, 256, 0, stream>>>(h1, fc1b, wl5, s1,
                                                          1024);
  fc_kernel<<<160 * 1, 256, 0, stream>>>(s1, fc2w, h2, 1024, 10, 1);
  plif_mean<<<(BATCH * 10 + 255) / 256, 256, 0, stream>>>(h2, fc2b, wl6, out,
                                                          10);
}

// Round 4
// 887.660 us; speedup vs baseline: 2.1099x; 2.1099x over previous
//
#include <hip/hip_runtime.h>
#include <math.h>

#define T_STEPS 5
#define BATCH 32

// ---------------------------------------------------------------------------
// Register-blocked 5x5 VALID conv, fp32, NCHW.
// Block = 256 thr: tid = cog*64 + rg*4 + cg  (cog wave-uniform!)
//   -> tile 32 rows (16 rg x 2) x 16 cols (4 cg x 4) x 16 co (4 cog x 4).
// Weights for this block's 16 co are transposed into LDS once: w[k][co],
// k = ci*25+kh*5+kw. Steady state (per ci): 48 global b32 input loads
// (immediate offsets), 25 ds_read_b128 weight broadcasts (wave-uniform
// address -> no conflicts), 800 FMAs. No barriers in the main loop.
// CLAMP: clamp flat in-plane offset (OOB only feeds discarded accs).
// ---------------------------------------------------------------------------
template <int CIN, int CB, int HIN, int WIN, int HOUT, int WOUT, int TILES_W,
          bool CLAMP>
__global__ __launch_bounds__(256, 3) void conv5_rb(
    const float* __restrict__ in, const float* __restrict__ wgt,
    float* __restrict__ out) {
  __shared__ __align__(16) float wlds[CIN * 25 * CB];
  const int tid = threadIdx.x;
  const int n = blockIdx.z;
  const int cob = blockIdx.y;
  const int Cout = gridDim.y * CB;

  for (int i = tid; i < CIN * 25 * CB; i += 256) {
    int co = i & (CB - 1);
    int k = i / CB;
    wlds[i] = wgt[(cob * CB + co) * (CIN * 25) + k];
  }
  __syncthreads();

  const int cog = tid >> 6;        // 0..3 wave-uniform
  const int rg = (tid >> 2) & 15;  // 0..15
  const int cg = tid & 3;          // 0..3
  const int th = blockIdx.x / TILES_W;
  const int twi = blockIdx.x - th * TILES_W;
  const int row0 = th * 32 + rg * 2;
  const int col0 = twi * 16 + cg * 4;

  float acc[4][2][4];
#pragma unroll
  for (int a = 0; a < 4; ++a)
#pragma unroll
    for (int b = 0; b < 2; ++b)
#pragma unroll
      for (int c = 0; c < 4; ++c) acc[a][b][c] = 0.f;

  const float* ip =
      in + (long)n * CIN * (HIN * WIN) + row0 * WIN + col0;  // !CLAMP path

  for (int ci = 0; ci < CIN; ++ci) {
    float win[6][8];
    if (CLAMP) {
      const float* pp = in + ((long)n * CIN + ci) * (HIN * WIN);
#pragma unroll
      for (int rr = 0; rr < 6; ++rr)
#pragma unroll
        for (int jj = 0; jj < 8; ++jj) {
          int off = (row0 + rr) * WIN + (col0 + jj);
          off = off < HIN * WIN - 1 ? off : HIN * WIN - 1;
          win[rr][jj] = pp[off];
        }
    } else {
#pragma unroll
      for (int rr = 0; rr < 6; ++rr)
#pragma unroll
        for (int jj = 0; jj < 8; ++jj) win[rr][jj] = ip[rr * WIN + jj];
      ip += HIN * WIN;
    }

    const float* wp = &wlds[ci * 25 * CB + cog * 4];
#pragma unroll
    for (int kh = 0; kh < 5; ++kh)
#pragma unroll
      for (int kw = 0; kw < 5; ++kw) {
        float4 wv = *reinterpret_cast<const float4*>(wp + (kh * 5 + kw) * CB);
        float wa[4] = {wv.x, wv.y, wv.z, wv.w};
#pragma unroll
        for (int co = 0; co < 4; ++co)
#pragma unroll
          for (int r2 = 0; r2 < 2; ++r2)
#pragma unroll
            for (int c4 = 0; c4 < 4; ++c4)
              acc[co][r2][c4] =
                  fmaf(win[kh + r2][kw + c4], wa[co], acc[co][r2][c4]);
      }
  }

#pragma unroll
  for (int co = 0; co < 4; ++co) {
    int coG = cob * CB + cog * 4 + co;
    float* op = out + ((long)n * Cout + coG) * (HOUT * WOUT);
#pragma unroll
    for (int r2 = 0; r2 < 2; ++r2) {
      int ho = row0 + r2;
      if (ho < HOUT) {
#pragma unroll
        for (int c4 = 0; c4 < 4; ++c4) {
          int wo = col0 + c4;
          if (wo < WOUT) op[ho * WOUT + wo] = acc[co][r2][c4];
        }
      }
    }
  }
}

// conv4: (160,32,12,12) -> (160,64,8,8). No LDS: 1 px x 4 co per thread,
// weights via wave-uniform-address vector loads (1 transaction, L1-hot).
__global__ __launch_bounds__(256) void conv4_rb(const float* __restrict__ in,
                                                const float* __restrict__ wgt,
                                                float* __restrict__ out) {
  const int tid = threadIdx.x;
  const int px = tid & 63;
  const int cog = tid >> 6;      // wave-uniform
  const int cob = blockIdx.x;    // 0..3
  const int n = blockIdx.y;      // 0..159
  const int r = px >> 3, c = px & 7;
  const int co0 = cob * 16 + cog * 4;
  float acc[4] = {0.f, 0.f, 0.f, 0.f};
  const float* ip = in + (long)n * 32 * 144 + r * 12 + c;
  for (int ci = 0; ci < 32; ++ci) {
    float win[5][5];
#pragma unroll
    for (int kh = 0; kh < 5; ++kh)
#pragma unroll
      for (int kw = 0; kw < 5; ++kw) win[kh][kw] = ip[kh * 12 + kw];
    ip += 144;
    const float* wp = wgt + ci * 25;
#pragma unroll
    for (int kk = 0; kk < 25; ++kk) {
#pragma unroll
      for (int j = 0; j < 4; ++j) {
        float w = wp[(co0 + j) * 800 + kk];
        acc[j] = fmaf(win[kk / 5][kk % 5], w, acc[j]);
      }
    }
  }
  float* op = out + ((long)n * 64 + co0) * 64 + px;
#pragma unroll
  for (int j = 0; j < 4; ++j) op[j * 64] = acc[j];
}

// BN stats: two-stage deterministic partial sums in double ------------------
__global__ __launch_bounds__(256) void bn_partial(
    const float* __restrict__ y, int C, int M, int HW, double inv_hw,
    double* __restrict__ psum, double* __restrict__ psq, int S) {
  const int c = blockIdx.x / S;
  const int s = blockIdx.x - c * S;
  const int tid = threadIdx.x;
  double sum = 0.0, sumsq = 0.0;
  for (int i = s * 256 + tid; i < M; i += S * 256) {
    int n = (int)((double)i * inv_hw);
    int hw = i - n * HW;
    if (hw < 0) { n--; hw += HW; }
    else if (hw >= HW) { n++; hw -= HW; }
    float v = y[((long)n * C + c) * (long)HW + hw];
    sum += (double)v;
    sumsq += (double)v * (double)v;
  }
  __shared__ double ls[256], ls2[256];
  ls[tid] = sum;
  ls2[tid] = sumsq;
  __syncthreads();
  for (int off = 128; off > 0; off >>= 1) {
    if (tid < off) {
      ls[tid] += ls[tid + off];
      ls2[tid] += ls2[tid + off];
    }
    __syncthreads();
  }
  if (tid == 0) {
    psum[blockIdx.x] = ls[0];
    psq[blockIdx.x] = ls2[0];
  }
}

__global__ void bn_finalize(const double* __restrict__ psum,
                            const double* __restrict__ psq,
                            const float* __restrict__ gamma,
                            const float* __restrict__ beta,
                            float* __restrict__ scale,
                            float* __restrict__ shift, int C, int S,
                            double invM) {
  int c = threadIdx.x;
  if (c >= C) return;
  double s = 0.0, s2 = 0.0;
  for (int i = 0; i < S; ++i) {
    s += psum[c * S + i];
    s2 += psq[c * S + i];
  }
  double m = s * invM;
  double var = s2 * invM - m * m;
  double r = 1.0 / sqrt(var + 1e-5);
  double sc = (double)gamma[c] * r;
  scale[c] = (float)sc;
  shift[c] = (float)((double)beta[c] - m * sc);
}

// Fused BN-affine + 5-step PLIF + 2x2 maxpool -------------------------------
__global__ __launch_bounds__(256) void plif_pool(
    const float* __restrict__ y, const float* __restrict__ scale,
    const float* __restrict__ shift, const float* __restrict__ wlif,
    float* __restrict__ p, int C, int H, int W, int PH, int PW,
    long t_stride) {
  int idx = blockIdx.x * 256 + threadIdx.x;
  int total = BATCH * C * PH * PW;
  if (idx >= total) return;
  int pw = idx % PW;
  int t2 = idx / PW;
  int ph = t2 % PH;
  t2 /= PH;
  int c = t2 % C;
  int b = t2 / C;
  const float sc = scale[c], sh = shift[c];
  const float decay = 1.f / (1.f + expf(-wlif[0]));
  const long base = (((long)b * C + c) * H + 2 * ph) * W + 2 * pw;
  const long pbase = (((long)b * C + c) * PH + ph) * PW + pw;
  const long pstr = (long)BATCH * C * PH * PW;
  float v0 = 0.f, v1 = 0.f, v2 = 0.f, v3 = 0.f;
#pragma unroll
  for (int t = 0; t < T_STEPS; ++t) {
    const float* yp = y + t * t_stride + base;
    float x0 = yp[0] * sc + sh;
    float x1 = yp[1] * sc + sh;
    float x2 = yp[W] * sc + sh;
    float x3 = yp[W + 1] * sc + sh;
    v0 += (x0 - v0) * decay;
    v1 += (x1 - v1) * decay;
    v2 += (x2 - v2) * decay;
    v3 += (x3 - v3) * decay;
    float s0 = (v0 >= 1.f) ? 1.f : 0.f;
    float s1 = (v1 >= 1.f) ? 1.f : 0.f;
    float s2 = (v2 >= 1.f) ? 1.f : 0.f;
    float s3 = (v3 >= 1.f) ? 1.f : 0.f;
    v0 = (v0 >= 1.f) ? 0.f : v0;
    v1 = (v1 >= 1.f) ? 0.f : v1;
    v2 = (v2 >= 1.f) ? 0.f : v2;
    v3 = (v3 >= 1.f) ? 0.f : v3;
    p[t * pstr + pbase] = fmaxf(fmaxf(s0, s1), fmaxf(s2, s3));
  }
}

// FC: out[n,o] = dot(x[n,:], w[o,:]) (bias added in PLIF). ------------------
__global__ __launch_bounds__(256) void fc_kernel(const float* __restrict__ x,
                                                 const float* __restrict__ w,
                                                 float* __restrict__ out,
                                                 int K, int O, int obpn) {
  int n = blockIdx.x / obpn;
  int o = (blockIdx.x - n * obpn) * 256 + threadIdx.x;
  if (o >= O) return;
  const float4* xr = reinterpret_cast<const float4*>(x + (long)n * K);
  const float4* wr = reinterpret_cast<const float4*>(w + (long)o * K);
  float acc = 0.f;
  for (int k = 0; k < K / 4; ++k) {
    float4 a = xr[k];
    float4 b = wr[k];
    acc += a.x * b.x + a.y * b.y + a.z * b.z + a.w * b.w;
  }
  out[(long)n * O + o] = acc;
}

// PLIF over time for FC activations (adds bias), writes spike seq -----------
__global__ __launch_bounds__(256) void plif_fc(const float* __restrict__ h,
                                               const float* __restrict__ bias,
                                               const float* __restrict__ wlif,
                                               float* __restrict__ s_out,
                                               int F) {
  int idx = blockIdx.x * 256 + threadIdx.x;
  if (idx >= BATCH * F) return;
  int f = idx % F;
  int b = idx / F;
  const float decay = 1.f / (1.f + expf(-wlif[0]));
  const float bi = bias[f];
  float v = 0.f;
#pragma unroll
  for (int t = 0; t < T_STEPS; ++t) {
    long off = ((long)(t * BATCH + b)) * F + f;
    float x = h[off] + bi;
    v += (x - v) * decay;
    float s = (v >= 1.f) ? 1.f : 0.f;
    v = (v >= 1.f) ? 0.f : v;
    s_out[off] = s;
  }
}

// Final PLIF + mean over T --------------------------------------------------
__global__ __launch_bounds__(256) void plif_mean(const float* __restrict__ h,
                                                 const float* __restrict__ bias,
                                                 const float* __restrict__ wlif,
                                                 float* __restrict__ out,
                                                 int O) {
  int idx = blockIdx.x * 256 + threadIdx.x;
  if (idx >= BATCH * O) return;
  int o = idx % O;
  int b = idx / O;
  const float decay = 1.f / (1.f + expf(-wlif[0]));
  const float bi = bias[o];
  float v = 0.f, sum = 0.f;
#pragma unroll
  for (int t = 0; t < T_STEPS; ++t) {
    float x = h[(long)(t * BATCH + b) * O + o] + bi;
    v += (x - v) * decay;
    float s = (v >= 1.f) ? 1.f : 0.f;
    v = (v >= 1.f) ? 0.f : v;
    sum += s;
  }
  out[(long)b * O + o] = sum / 5.0f;
}

// ---------------------------------------------------------------------------
extern "C" void kernel_launch(void* const* d_in, const int* in_sizes, int n_in,
                              void* d_out, int out_size, void* d_ws,
                              size_t ws_size, hipStream_t stream) {
  const float* x = (const float*)d_in[0];
  const float* wc1 = (const float*)d_in[1];
  const float* wc2 = (const float*)d_in[2];
  const float* wc3 = (const float*)d_in[3];
  const float* wc4 = (const float*)d_in[4];
  const float* g1 = (const float*)d_in[5];
  const float* b1 = (const float*)d_in[6];
  const float* g2 = (const float*)d_in[7];
  const float* b2 = (const float*)d_in[8];
  const float* g3 = (const float*)d_in[9];
  const float* b3 = (const float*)d_in[10];
  const float* g4 = (const float*)d_in[11];
  const float* b4 = (const float*)d_in[12];
  const float* wl1 = (const float*)d_in[13];
  const float* wl2 = (const float*)d_in[14];
  const float* wl3 = (const float*)d_in[15];
  const float* wl4 = (const float*)d_in[16];
  const float* wl5 = (const float*)d_in[17];
  const float* wl6 = (const float*)d_in[18];
  const float* fc1w = (const float*)d_in[19];
  const float* fc1b = (const float*)d_in[20];
  const float* fc2w = (const float*)d_in[21];
  const float* fc2b = (const float*)d_in[22];
  float* out = (float*)d_out;

  char* ws = (char*)d_ws;
  float* Y = (float*)ws;
  float* P = (float*)(ws + 68894720);
  char* Sb = ws + 68894720 + 39362560;
  double* psum = (double*)Sb;
  double* psq = psum + 64 * 32;
  float* scale = (float*)(psq + 64 * 32);
  float* shift = scale + 64;

  const int S = 32;

  // ---- block 1: conv1 on B=32 only (input replicated over T) ----
  conv5_rb<3, 16, 128, 128, 124, 124, 8, true>
      <<<dim3(4 * 8, 1, 32), 256, 0, stream>>>(x, wc1, Y);
  {
    int HW = 124 * 124, M = 32 * HW;
    bn_partial<<<16 * S, 256, 0, stream>>>(Y, 16, M, HW, 1.0 / HW, psum, psq, S);
    bn_finalize<<<1, 64, 0, stream>>>(psum, psq, g1, b1, scale, shift, 16, S,
                                      1.0 / (double)M);
  }
  {
    int total = BATCH * 16 * 62 * 62;
    plif_pool<<<(total + 255) / 256, 256, 0, stream>>>(
        Y, scale, shift, wl1, P, 16, 124, 124, 62, 62, 0L);
  }

  // ---- block 2: conv2 (160,16,62,62) -> (160,32,58,58) ----
  conv5_rb<16, 16, 62, 62, 58, 58, 4, false>
      <<<dim3(2 * 4, 2, 160), 256, 0, stream>>>(P, wc2, Y);
  {
    int HW = 58 * 58, M = 160 * HW;
    bn_partial<<<32 * S, 256, 0, stream>>>(Y, 32, M, HW, 1.0 / HW, psum, psq, S);
    bn_finalize<<<1, 64, 0, stream>>>(psum, psq, g2, b2, scale, shift, 32, S,
                                      1.0 / (double)M);
  }
  {
    int total = BATCH * 32 * 29 * 29;
    plif_pool<<<(total + 255) / 256, 256, 0, stream>>>(
        Y, scale, shift, wl2, P, 32, 58, 58, 29, 29, (long)BATCH * 32 * 58 * 58);
  }

  // ---- block 3: conv3 (160,32,29,29) -> (160,32,25,25) ----
  conv5_rb<32, 16, 29, 29, 25, 25, 2, false>
      <<<dim3(1 * 2, 2, 160), 256, 0, stream>>>(P, wc3, Y);
  {
    int HW = 25 * 25, M = 160 * HW;
    bn_partial<<<32 * S, 256, 0, stream>>>(Y, 32, M, HW, 1.0 / HW, psum, psq, S);
    bn_finalize<<<1, 64, 0, stream>>>(psum, psq, g3, b3, scale, shift, 32, S,
                                      1.0 / (double)M);
  }
  {
    int total = BATCH * 32 * 12 * 12;
    plif_pool<<<(total + 255) / 256, 256, 0, stream>>>(
        Y, scale, shift, wl3, P, 32, 25, 25, 12, 12, (long)BATCH * 32 * 25 * 25);
  }

  // ---- block 4: conv4 (160,32,12,12) -> (160,64,8,8) ----
  conv4_rb<<<dim3(4, 160), 256, 0, stream>>>(P, wc4, Y);
  {
    int HW = 8 * 8, M = 160 * HW;
    bn_partial<<<64 * S, 256, 0, stream>>>(Y, 64, M, HW, 1.0 / HW, psum, psq, S);
    bn_finalize<<<1, 64, 0, stream>>>(psum, psq, g4, b4, scale, shift, 64, S,
                                      1.0 / (double)M);
  }
  {
    int total = BATCH * 64 * 4 * 4;
    plif_pool<<<(total + 255) / 256, 256, 0, stream>>>(
        Y, scale, shift, wl4, P, 64, 8, 8, 4, 4, (long)BATCH * 64 * 8 * 8);
  }

  // ---- FC head ----
  float* h1 = Y;
  float* s1 = P;
  float* h2 = Y + 163840;
  fc_kernel<<<160 * 4, 256, 0, stream>>>(P, fc1w, h1, 1024, 1024, 4);
  plif_fc<<<(BATCH * 1024 + 255) / 256, 256, 0, stream>>>(h1, fc1b, wl5, s1,
                                                          1024);
  fc_kernel<<<160 * 1, 256, 0, stream>>>(s1, fc2w, h2, 1024, 10, 1);
  plif_mean<<<(BATCH * 10 + 255) / 256, 256, 0, stream>>>(h2, fc2b, wl6, out,
                                                          10);
}